// Round 8
// baseline (7535.620 us; speedup 1.0000x reference)
//
#include <hip/hip_runtime.h>
#include <math.h>

// SimpleRNN: out[b,t,u] = h_t where h_t = tanh(x_t @ Wx + bias + h_{t-1} @ Wh)
// Single fused kernel:
//   blocks 0..255   : scan (R3-exact core, setprio(1)). 4 u-slices x 64 groups
//                     (2 batches), stride-64 grouping (same-XCD heuristic).
//   blocks 256..8447: xp GEMM tiles (64x64), t-slab-major so xp[t<64] for all
//                     batches completes first. xp published via AGENT stores
//                     (MALL-visible; plain stores are NOT cross-XCD visible),
//                     then vmcnt-drained counter bump per (batch, t-slab).
// Scan consumes xp with agent loads gated on the slab counter (once / 64 steps).
// h exchange: data-as-flag agent atomics on sentinel-filled out (R3-proven).
// R7 lesson: sc0 loads don't give cross-CU visibility — agent scope only.
// R6 lesson: wall = 512 x chain; only chain-shortening helps.
// launch_bounds(1024,8) caps VGPR at 64 so scan+gemm co-reside per CU.

#define SENT 0xFFFFFFFFu
#define ALF(p)    __hip_atomic_load((p), __ATOMIC_RELAXED, __HIP_MEMORY_SCOPE_AGENT)
#define ASF(p, v) __hip_atomic_store((p), (v), __ATOMIC_RELAXED, __HIP_MEMORY_SCOPE_AGENT)
#define FMA4(A, W, H) { (A).x += (H)*(W).x; (A).y += (H)*(W).y; (A).z += (H)*(W).z; (A).w += (H)*(W).w; }

__global__ __launch_bounds__(1024, 8) void fused_rnn(
    const float* __restrict__ x,    // [65536, 256]
    const float* __restrict__ wx,   // [256, 512]
    const float* __restrict__ bias, // [512]
    const float* __restrict__ wh,   // [512, 512]
    float* __restrict__ xp,         // [128,512,512] workspace (agent-scope only)
    int* __restrict__ xpcnt,        // [128][8] zeroed slab counters
    float* __restrict__ out)        // [128,512,512] sentinel-prefilled
{
    __shared__ float smem[9216];    // scan: h_lds[1024]+red[8192]; gemm: As/Bs

    if (blockIdx.x < 256) {
        // ================= SCAN =================
        __builtin_amdgcn_s_setprio(1);   // favor scan waves over co-resident gemm
        float* h_lds = smem;             // [2][512]
        float* red   = smem + 1024;      // [32][2][128]

        const int tid = threadIdx.x;
        const int us  = blockIdx.x >> 6;   // u-slice 0..3 (stride-64: same XCD group)
        const int bg  = blockIdx.x & 63;   // batch-group 0..63
        const int u0  = us * 128;
        const int gq  = tid & 31;          // u-quad: u = u0+4gq ..
        const int s   = tid >> 5;          // k-slice: k = 16s ..
        const int kbase = s * 16;
        const size_t seq = 512 * 512;

        // Wh slice as plain array (R3 form: compiler streams from L2 under
        // the poll-phase shadow; measured faster than pinned AGPR residency).
        float4 w[16];
        #pragma unroll
        for (int i = 0; i < 16; ++i)
            w[i] = *(const float4*)&wh[(size_t)(kbase + i) * 512 + (u0 + 4 * gq)];

        const int ru = tid & 127;          // reduce role (tid<256)
        const int rb = (tid >> 7) & 1;
        const float* xpp = xp + (size_t)(bg * 2 + rb) * seq + u0 + ru;
        float*       hop = out + (size_t)(bg * 2 + rb) * seq + u0 + ru;
        const int* mycnt = xpcnt + (bg * 2 + rb) * 8;

        const int sb   = (tid >= 384) ? 1 : 0;       // stage role (tid<768)
        const int srem = tid - sb * 384;
        const int shk  = (srem < u0) ? srem : srem + 128;
        const float* pollp = out + (size_t)(bg * 2 + sb) * seq + shk;

        for (int t = 0; t < 512; ++t) {
            float xpv = 0.0f;
            if (tid < 256) {
                if ((t & 63) == 0) {       // gate on gemm slab completion
                    const int slab = t >> 6;
                    int c = __hip_atomic_load(&mycnt[slab], __ATOMIC_RELAXED,
                                              __HIP_MEMORY_SCOPE_AGENT);
                    int it = 0;
                    while (c < 8 && ++it < (1 << 22)) {
                        __builtin_amdgcn_s_sleep(2);
                        c = __hip_atomic_load(&mycnt[slab], __ATOMIC_RELAXED,
                                              __HIP_MEMORY_SCOPE_AGENT);
                    }
                }
                xpv = ALF(xpp + (size_t)t * 512);   // agent load (MALL-resident data)
            }

            if (t == 0) {
                smem[tid] = 0.0f;                   // zero h_lds[2][512]
            } else if (tid < 768) {
                const float* p = pollp + (size_t)(t - 1) * 512;
                float v = ALF(p);
                int it = 0;
                while (__float_as_uint(v) == SENT && ++it < (1 << 22)) {
                    if (it > 64) __builtin_amdgcn_s_sleep(1);   // spin hot first
                    v = ALF(p);
                }
                h_lds[sb * 512 + shk] = v;
            }
            __syncthreads();   // h_{t-1} staged

            float4 a0 = make_float4(0.f, 0.f, 0.f, 0.f);
            float4 a1 = make_float4(0.f, 0.f, 0.f, 0.f);
            const float* hb0 = h_lds + kbase;
            const float* hb1 = h_lds + 512 + kbase;
            #pragma unroll
            for (int i = 0; i < 4; ++i) {
                const float4 h0 = *(const float4*)(hb0 + 4 * i);
                const float4 h1 = *(const float4*)(hb1 + 4 * i);
                FMA4(a0, w[4*i+0], h0.x) FMA4(a0, w[4*i+1], h0.y)
                FMA4(a0, w[4*i+2], h0.z) FMA4(a0, w[4*i+3], h0.w)
                FMA4(a1, w[4*i+0], h1.x) FMA4(a1, w[4*i+1], h1.y)
                FMA4(a1, w[4*i+2], h1.z) FMA4(a1, w[4*i+3], h1.w)
            }
            *(float4*)&red[(s * 2 + 0) * 128 + 4 * gq] = a0;
            *(float4*)&red[(s * 2 + 1) * 128 + 4 * gq] = a1;
            __syncthreads();   // partials ready; h_lds reads done

            if (tid < 256) {
                float r = xpv;
                #pragma unroll
                for (int ss = 0; ss < 32; ++ss) r += red[(ss * 2 + rb) * 128 + ru];
                const float hn = tanhf(r);
                h_lds[rb * 512 + u0 + ru] = hn;     // own slice stays local
                ASF(hop + (size_t)t * 512, hn);     // publish (data IS the flag)
            }
            // 3rd barrier dropped: next iteration's post-stage __syncthreads
            // subsumes it (h_lds own-slice writes & red reuse both ordered
            // through that barrier; stage writes are disjoint from own slice).
        }
        return;
    }

    // ================= GEMM (t-slab-major) =================
    {
        const int g = blockIdx.x - 256;        // 0..8191
        const int tslab = g >> 10;             // 0..7  (t-range tslab*64 ..)
        const int rem = g & 1023;
        const int b  = rem >> 3;               // 0..127
        const int nx = rem & 7;                // 0..7
        const size_t m0 = (size_t)b * 512 + (size_t)tslab * 64;
        const int n0 = nx * 64;

        float* As = smem;                      // [32][69]
        float* Bs = smem + 32 * 69;            // [32][69]
        const int tid = threadIdx.x;
        const int tk = tid & 31, tr = tid >> 5;    // A loads
        const int bn = tid & 63, bk = tid >> 6;    // B loads
        const int tm = tid >> 6, tn = tid & 63;    // compute: rows tm*4.., col tn

        float acc0 = 0.f, acc1 = 0.f, acc2 = 0.f, acc3 = 0.f;
        for (int k0 = 0; k0 < 256; k0 += 32) {
            As[tk * 69 + tr]      = x[(m0 + tr) * 256 + (k0 + tk)];
            As[tk * 69 + tr + 32] = x[(m0 + tr + 32) * 256 + (k0 + tk)];
            Bs[bk * 69 + bn]        = wx[(size_t)(k0 + bk) * 512 + (n0 + bn)];
            Bs[(bk + 16) * 69 + bn] = wx[(size_t)(k0 + bk + 16) * 512 + (n0 + bn)];
            __syncthreads();
            #pragma unroll
            for (int k = 0; k < 32; ++k) {
                const float bv = Bs[k * 69 + tn];
                const float* ar = As + k * 69 + tm * 4;   // broadcast across wave
                acc0 += ar[0] * bv; acc1 += ar[1] * bv;
                acc2 += ar[2] * bv; acc3 += ar[3] * bv;
            }
            __syncthreads();
        }
        const float bs = bias[n0 + tn];
        float* xr = xp + (m0 + tm * 4) * 512 + n0 + tn;
        ASF(xr + 0 * 512, acc0 + bs);   // agent stores: MALL-visible to scan
        ASF(xr + 1 * 512, acc1 + bs);
        ASF(xr + 2 * 512, acc2 + bs);
        ASF(xr + 3 * 512, acc3 + bs);
        asm volatile("s_waitcnt vmcnt(0)" ::: "memory");  // stores complete
        __syncthreads();                                  // ... for all waves
        if (tid == 0)
            __hip_atomic_fetch_add(&xpcnt[b * 8 + tslab], 1,
                                   __ATOMIC_RELAXED, __HIP_MEMORY_SCOPE_AGENT);
    }
}

// ================= fallback: unfused R3 path (ws >= xp only) =================
__global__ __launch_bounds__(256) void xp_gemm(
    const float* __restrict__ x, const float* __restrict__ wx,
    const float* __restrict__ bias, float* __restrict__ xp)
{
    __shared__ float As[32][68];
    __shared__ float Bs[32][68];
    const int tid = threadIdx.x;
    const int m0 = blockIdx.y * 64;
    const int n0 = blockIdx.x * 64;
    const int tm = tid / 16;
    const int tn = tid % 16;
    float acc[4][4] = {};
    for (int k0 = 0; k0 < 256; k0 += 32) {
        {
            const int kk = tid % 32, r0 = tid / 32;
            #pragma unroll
            for (int rr = 0; rr < 8; ++rr)
                As[kk][r0 + rr * 8] = x[(size_t)(m0 + r0 + rr * 8) * 256 + (k0 + kk)];
        }
        {
            const int nn = tid % 64, r0 = tid / 64;
            #pragma unroll
            for (int rr = 0; rr < 8; ++rr)
                Bs[r0 + rr * 4][nn] = wx[(size_t)(k0 + r0 + rr * 4) * 512 + (n0 + nn)];
        }
        __syncthreads();
        #pragma unroll
        for (int kk = 0; kk < 32; ++kk) {
            const float4 a = *(const float4*)&As[kk][tm * 4];
            const float4 b = *(const float4*)&Bs[kk][tn * 4];
            const float av[4] = {a.x, a.y, a.z, a.w};
            const float bv[4] = {b.x, b.y, b.z, b.w};
            #pragma unroll
            for (int i = 0; i < 4; ++i)
                #pragma unroll
                for (int j = 0; j < 4; ++j)
                    acc[i][j] += av[i] * bv[j];
        }
        __syncthreads();
    }
    #pragma unroll
    for (int i = 0; i < 4; ++i)
        #pragma unroll
        for (int j = 0; j < 4; ++j)
            xp[(size_t)(m0 + tm * 4 + i) * 512 + (n0 + tn * 4 + j)] =
                acc[i][j] + bias[n0 + tn * 4 + j];
}

__global__ __launch_bounds__(1024) void rnn_scan_r3(
    const float* __restrict__ wh, const float* __restrict__ xp,
    float* __restrict__ out)
{
    __shared__ float h_lds[2][512];
    __shared__ float red[32][2][128];
    const int tid = threadIdx.x;
    const int us  = blockIdx.x >> 6;
    const int bg  = blockIdx.x & 63;
    const int u0  = us * 128;
    const int gq  = tid & 31;
    const int s   = tid >> 5;
    const int kbase = s * 16;
    const size_t seq = 512 * 512;

    float4 w[16];
    #pragma unroll
    for (int i = 0; i < 16; ++i)
        w[i] = *(const float4*)&wh[(size_t)(kbase + i) * 512 + (u0 + 4 * gq)];

    const int ru = tid & 127;
    const int rb = (tid >> 7) & 1;
    const float* xpp = xp + (size_t)(bg * 2 + rb) * seq + u0 + ru;
    float*       hop = out + (size_t)(bg * 2 + rb) * seq + u0 + ru;
    const int sb   = (tid >= 384) ? 1 : 0;
    const int srem = tid - sb * 384;
    const int shk  = (srem < u0) ? srem : srem + 128;
    const float* pollp = out + (size_t)(bg * 2 + sb) * seq + shk;

    for (int t = 0; t < 512; ++t) {
        float xpv = 0.0f;
        if (tid < 256) xpv = xpp[(size_t)t * 512];
        if (t == 0) {
            ((float*)h_lds)[tid] = 0.0f;
        } else if (tid < 768) {
            const float* p = pollp + (size_t)(t - 1) * 512;
            float v = ALF(p);
            int it = 0;
            while (__float_as_uint(v) == SENT && ++it < (1 << 22)) {
                if (it > 64) __builtin_amdgcn_s_sleep(1);
                v = ALF(p);
            }
            h_lds[sb][shk] = v;
        }
        __syncthreads();
        float4 a0 = make_float4(0.f, 0.f, 0.f, 0.f);
        float4 a1 = make_float4(0.f, 0.f, 0.f, 0.f);
        const float* hb0 = &h_lds[0][kbase];
        const float* hb1 = &h_lds[1][kbase];
        #pragma unroll
        for (int i = 0; i < 4; ++i) {
            const float4 h0 = *(const float4*)(hb0 + 4 * i);
            const float4 h1 = *(const float4*)(hb1 + 4 * i);
            FMA4(a0, w[4*i+0], h0.x) FMA4(a0, w[4*i+1], h0.y)
            FMA4(a0, w[4*i+2], h0.z) FMA4(a0, w[4*i+3], h0.w)
            FMA4(a1, w[4*i+0], h1.x) FMA4(a1, w[4*i+1], h1.y)
            FMA4(a1, w[4*i+2], h1.z) FMA4(a1, w[4*i+3], h1.w)
        }
        *(float4*)&red[s][0][4 * gq] = a0;
        *(float4*)&red[s][1][4 * gq] = a1;
        __syncthreads();
        if (tid < 256) {
            float r = xpv;
            #pragma unroll
            for (int ss = 0; ss < 32; ++ss) r += red[ss][rb][ru];
            const float hn = tanhf(r);
            h_lds[rb][u0 + ru] = hn;
            ASF(hop + (size_t)t * 512, hn);
        }
        __syncthreads();
    }
}

// ---- minimal fallback (no usable ws): single block per batch pair ----
__global__ __launch_bounds__(1024, 4) void rnn_scan2(
    const float* __restrict__ wh, float* __restrict__ out)
{
    __shared__ float h_lds[2][512];
    __shared__ float red[8][2][512];
    const int tid = threadIdx.x;
    const int g = tid & 127;
    const int s = tid >> 7;
    const int b = tid >> 9;
    const int u = tid & 511;
    float* seqb = out + (size_t)(2 * blockIdx.x + b) * 512 * 512;
    h_lds[b][u] = 0.0f;
    __syncthreads();
    const float4* __restrict__ whv = (const float4*)wh;
    const int kbase = s * 64;
    for (int t = 0; t < 512; ++t) {
        const float xpv = seqb[(size_t)t * 512 + u];
        float4 a0 = make_float4(0.f, 0.f, 0.f, 0.f);
        float4 a1 = make_float4(0.f, 0.f, 0.f, 0.f);
        #pragma unroll 4
        for (int kk = 0; kk < 64; kk += 4) {
            const int k = kbase + kk;
            const float4 h0 = *(const float4*)&h_lds[0][k];
            const float4 h1 = *(const float4*)&h_lds[1][k];
            const float4 v0 = whv[(k + 0) * 128 + g];
            const float4 v1 = whv[(k + 1) * 128 + g];
            const float4 v2 = whv[(k + 2) * 128 + g];
            const float4 v3 = whv[(k + 3) * 128 + g];
            FMA4(a0, v0, h0.x) FMA4(a0, v1, h0.y) FMA4(a0, v2, h0.z) FMA4(a0, v3, h0.w)
            FMA4(a1, v0, h1.x) FMA4(a1, v1, h1.y) FMA4(a1, v2, h1.z) FMA4(a1, v3, h1.w)
        }
        *(float4*)&red[s][0][4 * g] = a0;
        *(float4*)&red[s][1][4 * g] = a1;
        __syncthreads();
        float r = xpv;
        #pragma unroll
        for (int ss = 0; ss < 8; ++ss) r += red[ss][b][u];
        const float hn = tanhf(r);
        h_lds[b][u] = hn;
        seqb[(size_t)t * 512 + u] = hn;
        __syncthreads();
    }
}

extern "C" void kernel_launch(void* const* d_in, const int* in_sizes, int n_in,
                              void* d_out, int out_size, void* d_ws, size_t ws_size,
                              hipStream_t stream) {
    const float* x    = (const float*)d_in[0];  // [128,512,256]
    const float* wx   = (const float*)d_in[1];  // [256,512]
    const float* wh   = (const float*)d_in[2];  // [512,512]
    const float* bias = (const float*)d_in[3];  // [512]
    float* out = (float*)d_out;                 // [128,512,512]

    const size_t xp_bytes  = (size_t)128 * 512 * 512 * sizeof(float);
    const size_t cnt_bytes = 128 * 8 * sizeof(int);

    if (d_ws != nullptr && ws_size >= xp_bytes + cnt_bytes) {
        // Primary: fused scan+gemm. out sentinel-filled; xp + slab counters in ws.
        hipMemsetAsync(d_out, 0xFF, xp_bytes, stream);
        int* cnt = (int*)((char*)d_ws + xp_bytes);
        hipMemsetAsync(cnt, 0, cnt_bytes, stream);
        fused_rnn<<<256 + 8192, 1024, 0, stream>>>(
            x, wx, bias, wh, (float*)d_ws, cnt, out);
    } else if (d_ws != nullptr && ws_size >= xp_bytes) {
        hipMemsetAsync(d_out, 0xFF, xp_bytes, stream);
        dim3 g1(512 / 64, 65536 / 64);
        xp_gemm<<<g1, 256, 0, stream>>>(x, wx, bias, (float*)d_ws);
        rnn_scan_r3<<<256, 1024, 0, stream>>>(wh, (const float*)d_ws, out);
    } else {
        dim3 g1(512 / 64, 65536 / 64);
        xp_gemm<<<g1, 256, 0, stream>>>(x, wx, bias, out);
        rnn_scan2<<<64, 1024, 0, stream>>>(wh, out);
    }
}

// Round 9
// 1290.488 us; speedup vs baseline: 5.8394x; 5.8394x over previous
//
#include <hip/hip_runtime.h>
#include <math.h>

// SimpleRNN: out[b,t,u] = h_t where h_t = tanh(x_t @ Wx + bias + h_{t-1} @ Wh)
// Phase 1: xp_gemm_sent -- xp = x @ Wx + bias -> ws; ALSO sentinel-fills its
//          out region (0xFF = -NaN, tanh never produces it) -> no separate memset.
// Phase 2: rnn_scan9 -- R3-exact decomposition (best measured: 2.02 us/step):
//          256 blocks = 4 u-slices x 64 groups (2 batches), 1024 thr.
//          Wh[:,128-slice] in 16 named float4 (compiler keeps resident/AGPR).
//          h exchange: data-as-flag relaxed AGENT atomics on out (R7 lesson:
//          sc0 has no cross-CU visibility; agent scope is the only option).
//          Trims vs R3 (validated in R8's passing scan core):
//            - poll spins hot 32 iters before s_sleep (MALL RT ~3 dep loads)
//            - barrier-3 dropped (remote h_lds slices dead after bar2; own-slice
//              and red writes ordered through next iteration's bar1)
// R8 lesson: never fuse a spin-wait kernel with a bandwidth-bound producer --
// agent-scope polling eats HBM/MALL bandwidth and dispatch order isn't ours.
// R6 lesson: wall = 512 x chain length; batch stagger only lengthens the chain.
// R5 lesson: dedupe h through LDS; never per-thread agent loads.

#define SENT 0xFFFFFFFFu
#define ALF(p)    __hip_atomic_load((p), __ATOMIC_RELAXED, __HIP_MEMORY_SCOPE_AGENT)
#define ASF(p, v) __hip_atomic_store((p), (v), __ATOMIC_RELAXED, __HIP_MEMORY_SCOPE_AGENT)
#define FMA4(A, W, H) { (A).x += (H)*(W).x; (A).y += (H)*(W).y; (A).z += (H)*(W).z; (A).w += (H)*(W).w; }

// ---- GEMM: xp -> ws, sentinel -> out (same 64x64 region), 256 threads ----
__global__ __launch_bounds__(256) void xp_gemm_sent(
    const float* __restrict__ x,    // [65536, 256]
    const float* __restrict__ wx,   // [256, 512]
    const float* __restrict__ bias, // [512]
    float* __restrict__ xp,         // [65536, 512] (workspace)
    float* __restrict__ out)        // [65536, 512] -> sentinel fill
{
    __shared__ float As[32][68];
    __shared__ float Bs[32][68];

    const int tid = threadIdx.x;
    const int m0 = blockIdx.y * 64;
    const int n0 = blockIdx.x * 64;
    const int tm = tid / 16;
    const int tn = tid % 16;

    // Sentinel-fill this block's out tile first (fire-and-forget, overlaps GEMM).
    {
        const float s = __uint_as_float(SENT);
        const float4 sv = make_float4(s, s, s, s);
        const int r = tid >> 4;              // 0..15
        const int c = (tid & 15) * 4;        // 0..60
        float* op = out + (size_t)m0 * 512 + n0;
        #pragma unroll
        for (int i = 0; i < 4; ++i)
            *(float4*)&op[(size_t)(r + 16 * i) * 512 + c] = sv;
    }

    float acc[4][4] = {};

    for (int k0 = 0; k0 < 256; k0 += 32) {
        {
            const int kk = tid % 32, r0 = tid / 32;
            #pragma unroll
            for (int rr = 0; rr < 8; ++rr)
                As[kk][r0 + rr * 8] = x[(size_t)(m0 + r0 + rr * 8) * 256 + (k0 + kk)];
        }
        {
            const int nn = tid % 64, r0 = tid / 64;
            #pragma unroll
            for (int rr = 0; rr < 8; ++rr)
                Bs[r0 + rr * 4][nn] = wx[(size_t)(k0 + r0 + rr * 4) * 512 + (n0 + nn)];
        }
        __syncthreads();

        #pragma unroll
        for (int kk = 0; kk < 32; ++kk) {
            const float4 a = *(const float4*)&As[kk][tm * 4];
            const float4 b = *(const float4*)&Bs[kk][tn * 4];
            const float av[4] = {a.x, a.y, a.z, a.w};
            const float bv[4] = {b.x, b.y, b.z, b.w};
            #pragma unroll
            for (int i = 0; i < 4; ++i)
                #pragma unroll
                for (int j = 0; j < 4; ++j)
                    acc[i][j] += av[i] * bv[j];
        }
        __syncthreads();
    }

    #pragma unroll
    for (int i = 0; i < 4; ++i)
        #pragma unroll
        for (int j = 0; j < 4; ++j)
            xp[(size_t)(m0 + tm * 4 + i) * 512 + (n0 + tn * 4 + j)] =
                acc[i][j] + bias[n0 + tn * 4 + j];
}

// ---- scan: R3-exact core + hot-spin poll + barrier-3 dropped ----
__global__ __launch_bounds__(1024) void rnn_scan9(
    const float* __restrict__ wh,   // [512, 512] row-major (k, u)
    const float* __restrict__ xp,   // [128, 512, 512] (workspace)
    float* __restrict__ out)        // [128, 512, 512] sentinel-prefilled
{
    __shared__ float h_lds[2][512];        // 4 KB
    __shared__ float red[32][2][128];      // 32 KB

    const int tid = threadIdx.x;
    const int us  = blockIdx.x >> 6;   // u-slice 0..3 (stride-64 grouping: same XCD)
    const int bg  = blockIdx.x & 63;   // batch-group 0..63
    const int u0  = us * 128;
    const int g   = tid & 31;          // u-quad: u = u0+4g .. u0+4g+3
    const int s   = tid >> 5;          // k-slice: k = 16s .. 16s+15
    const int kbase = s * 16;
    const size_t seq = 512 * 512;

    // Wh slice in 16 named float4 (R3 form -- measured best; compiler keeps
    // these resident in the unified VGPR/AGPR file).
    const float* wr = &wh[(size_t)kbase * 512 + (u0 + 4 * g)];
    const float4 w0  = *(const float4*)(wr + 0  * 512);
    const float4 w1  = *(const float4*)(wr + 1  * 512);
    const float4 w2  = *(const float4*)(wr + 2  * 512);
    const float4 w3  = *(const float4*)(wr + 3  * 512);
    const float4 w4  = *(const float4*)(wr + 4  * 512);
    const float4 w5  = *(const float4*)(wr + 5  * 512);
    const float4 w6  = *(const float4*)(wr + 6  * 512);
    const float4 w7  = *(const float4*)(wr + 7  * 512);
    const float4 w8  = *(const float4*)(wr + 8  * 512);
    const float4 w9  = *(const float4*)(wr + 9  * 512);
    const float4 w10 = *(const float4*)(wr + 10 * 512);
    const float4 w11 = *(const float4*)(wr + 11 * 512);
    const float4 w12 = *(const float4*)(wr + 12 * 512);
    const float4 w13 = *(const float4*)(wr + 13 * 512);
    const float4 w14 = *(const float4*)(wr + 14 * 512);
    const float4 w15 = *(const float4*)(wr + 15 * 512);

    // reduce role (tid < 256): output unit u0+ru of batch rb
    const int ru = tid & 127;
    const int rb = (tid >> 7) & 1;
    const float* xpp = xp + (size_t)(bg * 2 + rb) * seq + u0 + ru;   // + t*512
    float*       hop = out + (size_t)(bg * 2 + rb) * seq + u0 + ru;  // + t*512

    // stage role (tid < 768): poll remote h element (sb, shk)
    const int sb   = (tid >= 384) ? 1 : 0;
    const int srem = tid - sb * 384;                   // 0..383
    const int shk  = (srem < u0) ? srem : srem + 128;  // skip own slice
    const float* pollp = out + (size_t)(bg * 2 + sb) * seq + shk;    // + (t-1)*512

    for (int t = 0; t < 512; ++t) {
        float xpv = 0.0f;
        if (tid < 256) xpv = xpp[(size_t)t * 512];   // issued early, used post-reduce

        if (t == 0) {
            ((float*)h_lds)[tid] = 0.0f;             // 1024 threads cover [2][512]
        } else if (tid < 768) {
            const float* p = pollp + (size_t)(t - 1) * 512;
            float v = ALF(p);
            int it = 0;
            while (__float_as_uint(v) == SENT && ++it < (1 << 22)) {
                if (it > 32) __builtin_amdgcn_s_sleep(1);   // spin hot first
                v = ALF(p);
            }
            h_lds[sb][shk] = v;
        }
        __syncthreads();   // bar1: full h_{t-1} staged

        float4 a0 = make_float4(0.f, 0.f, 0.f, 0.f);
        float4 a1 = make_float4(0.f, 0.f, 0.f, 0.f);
        const float* hb0 = &h_lds[0][kbase];
        const float* hb1 = &h_lds[1][kbase];
        #define STEP4(W0, W1, W2, W3, OFF) { \
            const float4 h0 = *(const float4*)(hb0 + (OFF)); \
            const float4 h1 = *(const float4*)(hb1 + (OFF)); \
            FMA4(a0, W0, h0.x) FMA4(a0, W1, h0.y) FMA4(a0, W2, h0.z) FMA4(a0, W3, h0.w) \
            FMA4(a1, W0, h1.x) FMA4(a1, W1, h1.y) FMA4(a1, W2, h1.z) FMA4(a1, W3, h1.w) }
        STEP4(w0,  w1,  w2,  w3,  0)
        STEP4(w4,  w5,  w6,  w7,  4)
        STEP4(w8,  w9,  w10, w11, 8)
        STEP4(w12, w13, w14, w15, 12)
        #undef STEP4

        *(float4*)&red[s][0][4 * g] = a0;
        *(float4*)&red[s][1][4 * g] = a1;
        __syncthreads();   // bar2: partials ready; all h_lds remote reads done

        if (tid < 256) {
            float r = xpv;
            #pragma unroll
            for (int ss = 0; ss < 32; ++ss) r += red[ss][rb][ru];
            const float hn = tanhf(r);
            ASF(hop + (size_t)t * 512, hn);   // publish ASAP (data IS the flag)
            h_lds[rb][u0 + ru] = hn;          // own slice for next step
        }
        // bar3 dropped: remote h_lds slices are dead after bar2 (stage(t+1)
        // may overwrite them freely); own-slice & red(t+1) writes are ordered
        // through bar1(t+1), which every thread (incl. reducers) must reach.
    }
}

// ---- fallback (no usable ws): xp in out, single block per batch pair ----
__global__ __launch_bounds__(256) void xp_gemm_plain(
    const float* __restrict__ x, const float* __restrict__ wx,
    const float* __restrict__ bias, float* __restrict__ xp)
{
    __shared__ float As[32][68];
    __shared__ float Bs[32][68];
    const int tid = threadIdx.x;
    const int m0 = blockIdx.y * 64;
    const int n0 = blockIdx.x * 64;
    const int tm = tid / 16;
    const int tn = tid % 16;
    float acc[4][4] = {};
    for (int k0 = 0; k0 < 256; k0 += 32) {
        {
            const int kk = tid % 32, r0 = tid / 32;
            #pragma unroll
            for (int rr = 0; rr < 8; ++rr)
                As[kk][r0 + rr * 8] = x[(size_t)(m0 + r0 + rr * 8) * 256 + (k0 + kk)];
        }
        {
            const int nn = tid % 64, r0 = tid / 64;
            #pragma unroll
            for (int rr = 0; rr < 8; ++rr)
                Bs[r0 + rr * 4][nn] = wx[(size_t)(k0 + r0 + rr * 4) * 512 + (n0 + nn)];
        }
        __syncthreads();
        #pragma unroll
        for (int kk = 0; kk < 32; ++kk) {
            const float4 a = *(const float4*)&As[kk][tm * 4];
            const float4 b = *(const float4*)&Bs[kk][tn * 4];
            const float av[4] = {a.x, a.y, a.z, a.w};
            const float bv[4] = {b.x, b.y, b.z, b.w};
            #pragma unroll
            for (int i = 0; i < 4; ++i)
                #pragma unroll
                for (int j = 0; j < 4; ++j)
                    acc[i][j] += av[i] * bv[j];
        }
        __syncthreads();
    }
    #pragma unroll
    for (int i = 0; i < 4; ++i)
        #pragma unroll
        for (int j = 0; j < 4; ++j)
            xp[(size_t)(m0 + tm * 4 + i) * 512 + (n0 + tn * 4 + j)] =
                acc[i][j] + bias[n0 + tn * 4 + j];
}

__global__ __launch_bounds__(1024, 4) void rnn_scan2(
    const float* __restrict__ wh, float* __restrict__ out)
{
    __shared__ float h_lds[2][512];
    __shared__ float red[8][2][512];
    const int tid = threadIdx.x;
    const int g = tid & 127;
    const int s = tid >> 7;
    const int b = tid >> 9;
    const int u = tid & 511;
    float* seqb = out + (size_t)(2 * blockIdx.x + b) * 512 * 512;
    h_lds[b][u] = 0.0f;
    __syncthreads();
    const float4* __restrict__ whv = (const float4*)wh;
    const int kbase = s * 64;
    for (int t = 0; t < 512; ++t) {
        const float xpv = seqb[(size_t)t * 512 + u];
        float4 a0 = make_float4(0.f, 0.f, 0.f, 0.f);
        float4 a1 = make_float4(0.f, 0.f, 0.f, 0.f);
        #pragma unroll 4
        for (int kk = 0; kk < 64; kk += 4) {
            const int k = kbase + kk;
            const float4 h0 = *(const float4*)&h_lds[0][k];
            const float4 h1 = *(const float4*)&h_lds[1][k];
            const float4 v0 = whv[(k + 0) * 128 + g];
            const float4 v1 = whv[(k + 1) * 128 + g];
            const float4 v2 = whv[(k + 2) * 128 + g];
            const float4 v3 = whv[(k + 3) * 128 + g];
            FMA4(a0, v0, h0.x) FMA4(a0, v1, h0.y) FMA4(a0, v2, h0.z) FMA4(a0, v3, h0.w)
            FMA4(a1, v0, h1.x) FMA4(a1, v1, h1.y) FMA4(a1, v2, h1.z) FMA4(a1, v3, h1.w)
        }
        *(float4*)&red[s][0][4 * g] = a0;
        *(float4*)&red[s][1][4 * g] = a1;
        __syncthreads();
        float r = xpv;
        #pragma unroll
        for (int ss = 0; ss < 8; ++ss) r += red[ss][b][u];
        const float hn = tanhf(r);
        h_lds[b][u] = hn;
        seqb[(size_t)t * 512 + u] = hn;
        __syncthreads();
    }
}

extern "C" void kernel_launch(void* const* d_in, const int* in_sizes, int n_in,
                              void* d_out, int out_size, void* d_ws, size_t ws_size,
                              hipStream_t stream) {
    const float* x    = (const float*)d_in[0];  // [128,512,256]
    const float* wx   = (const float*)d_in[1];  // [256,512]
    const float* wh   = (const float*)d_in[2];  // [512,512]
    const float* bias = (const float*)d_in[3];  // [512]
    float* out = (float*)d_out;                 // [128,512,512]

    const size_t xp_bytes = (size_t)128 * 512 * 512 * sizeof(float);
    dim3 g1(512 / 64, 65536 / 64);

    if (d_ws != nullptr && ws_size >= xp_bytes) {
        // Primary: GEMM (xp->ws, sentinel->out) then data-as-flag scan.
        xp_gemm_sent<<<g1, 256, 0, stream>>>(x, wx, bias, (float*)d_ws, out);
        rnn_scan9<<<256, 1024, 0, stream>>>(wh, (const float*)d_ws, out);
    } else {
        xp_gemm_plain<<<g1, 256, 0, stream>>>(x, wx, bias, out);
        rnn_scan2<<<64, 1024, 0, stream>>>(wh, out);
    }
}